// Round 1
// baseline (260.641 us; speedup 1.0000x reference)
//
#include <hip/hip_runtime.h>
#include <hip/hip_bf16.h>
#include <math.h>

// Problem constants (fixed by setup_inputs)
#define BB 2
#define HH2 64
#define WW2 64
#define CC 96
#define DD 96
#define NN 16
#define RR 6
#define KK 4
#define LL 4096           // H*W
#define CH 32             // scan chunk length
#define NC 128            // number of chunks (CH*NC == LL)

__device__ __forceinline__ float wsum(float v){
#pragma unroll
  for (int o = 32; o > 0; o >>= 1) v += __shfl_xor(v, o, 64);
  return v;
}

// map scan index l (direction k) -> spatial pixel index (h*W + w)
__device__ __forceinline__ int pos_of(int k, int l){
  int ll = (k & 2) ? (LL - 1 - l) : l;
  if (k & 1) return ((ll & 63) << 6) | (ll >> 6);   // w-major -> h*W+w
  return ll;
}

__device__ __forceinline__ float siluf(float v){ return v / (1.f + __expf(-v)); }

// ---------------- Kernel 1: pre-LN + in_proj (split xh, z) ----------------
// grid: B*L/4 blocks x 256 threads; one wave per pixel
__global__ void k1_ln_inproj(const float* __restrict__ x,
                             const float* __restrict__ g, const float* __restrict__ bta,
                             const float* __restrict__ W,   // (192,96)
                             float* __restrict__ xh, float* __restrict__ z){
  int wave = threadIdx.x >> 6, lane = threadIdx.x & 63;
  int pix  = blockIdx.x * 4 + wave;           // 0..B*L-1
  __shared__ float xn_s[4][CC];
  const float* xp = x + (size_t)pix * CC;
  float a  = xp[lane];
  float b2 = (lane < 32) ? xp[64 + lane] : 0.f;
  float s  = wsum(a + b2);
  float sq = wsum(a * a + b2 * b2);
  float mu = s * (1.f / 96.f);
  float var = sq * (1.f / 96.f) - mu * mu;
  float rs = rsqrtf(var + 1e-5f);
  xn_s[wave][lane] = (a - mu) * rs * g[lane] + bta[lane];
  if (lane < 32) xn_s[wave][64 + lane] = (b2 - mu) * rs * g[64 + lane] + bta[64 + lane];
  __syncthreads();
  const float* xn = xn_s[wave];
#pragma unroll
  for (int j0 = 0; j0 < 3; j0++){
    int j = lane + j0 * 64;
    const float* wr = W + (size_t)j * CC;
    float acc = 0.f;
#pragma unroll 8
    for (int c = 0; c < CC; c++) acc += xn[c] * wr[c];
    if (j < DD) xh[(size_t)pix * DD + j] = acc;
    else        z [(size_t)pix * DD + (j - DD)] = acc;
  }
}

// ---------------- Kernel 2: depthwise 3x3 conv + bias + SiLU ----------------
// thread = ((b*L + pos)*D + d), d inner (coalesced); out xc (B,L,D)
__global__ void k2_conv(const float* __restrict__ xh,
                        const float* __restrict__ cw, const float* __restrict__ cb,
                        float* __restrict__ xc){
  int idx = blockIdx.x * 256 + threadIdx.x;
  if (idx >= BB * LL * DD) return;
  int d   = idx % DD;
  int pix = (idx / DD) % LL;
  int b   = idx / (DD * LL);
  int h = pix >> 6, w = pix & 63;
  float acc = cb[d];
#pragma unroll
  for (int kh = 0; kh < 3; kh++){
    int hh = h + kh - 1;
    if (hh < 0 || hh >= HH2) continue;
#pragma unroll
    for (int kw = 0; kw < 3; kw++){
      int ww = w + kw - 1;
      if (ww < 0 || ww >= WW2) continue;
      acc += xh[((size_t)(b * LL) + (hh * WW2 + ww)) * DD + d] * cw[d * 9 + kh * 3 + kw];
    }
  }
  xc[idx] = siluf(acc);
}

// ---------------- Kernel 3: x_proj (38 outs) + dt_proj + softplus ----------------
// grid: B*K*L/4 blocks x 256 threads; one wave per (b,k,l)
__global__ void k3_xproj(const float* __restrict__ xc,
                         const float* __restrict__ xpw,   // (K,38,96)
                         const float* __restrict__ dtw,   // (K,96,6)
                         const float* __restrict__ dtb,   // (K,96)
                         float* __restrict__ dt,          // (B,K,L,D)
                         float* __restrict__ Bs,          // (B,K,L,N)
                         float* __restrict__ Cs){         // (B,K,L,N)
  int wave = threadIdx.x >> 6, lane = threadIdx.x & 63;
  int wid  = blockIdx.x * 4 + wave;       // 0..B*K*L-1
  int l = wid & (LL - 1);
  int k = (wid >> 12) & 3;
  int b = wid >> 14;
  __shared__ float xv_s[4][CC];
  __shared__ float proj_s[4][RR];
  int pos = pos_of(k, l);
  const float* xp = xc + ((size_t)b * LL + pos) * DD;
  xv_s[wave][lane] = xp[lane];
  if (lane < 32) xv_s[wave][64 + lane] = xp[64 + lane];
  __syncthreads();
  const float* xv = xv_s[wave];
  if (lane < RR + 2 * NN){   // 38 projection rows
    const float* wr = xpw + ((size_t)k * 38 + lane) * CC;
    float acc = 0.f;
#pragma unroll 8
    for (int c = 0; c < CC; c++) acc += xv[c] * wr[c];
    size_t bkl = ((size_t)(b * KK + k) * LL + l);
    if (lane < RR)            proj_s[wave][lane] = acc;
    else if (lane < RR + NN)  Bs[bkl * NN + (lane - RR)] = acc;
    else                      Cs[bkl * NN + (lane - RR - NN)] = acc;
  }
  __syncthreads();
  const float* proj = proj_s[wave];
  size_t bkl = ((size_t)(b * KK + k) * LL + l);
#pragma unroll
  for (int d = lane; d < DD; d += 64){
    const float* wr = dtw + ((size_t)k * DD + d) * RR;
    float acc = dtb[k * DD + d];
#pragma unroll
    for (int r = 0; r < RR; r++) acc += proj[r] * wr[r];
    acc = (acc > 20.f) ? acc : log1pf(expf(acc));   // softplus
    dt[bkl * DD + d] = acc;
  }
}

// ---------------- Kernel 4a: chunk-local scan (state + A-product) ----------------
// grid: B*K*NC blocks x 128 threads (d = tid, active d<96)
__global__ void k4a_scanA(const float* __restrict__ dt, const float* __restrict__ xc,
                          const float* __restrict__ Bsv, const float* __restrict__ Alog,
                          float* __restrict__ Hc, float* __restrict__ Pc){
  int blk = blockIdx.x;
  int chunk = blk & (NC - 1);
  int k = (blk >> 7) & 3;
  int b = blk >> 9;
  __shared__ float lB[CH * NN];
  {
    const float* src = Bsv + ((size_t)(b * KK + k) * LL + chunk * CH) * NN;
    for (int i = threadIdx.x; i < CH * NN; i += 128) lB[i] = src[i];
  }
  __syncthreads();
  int d = threadIdx.x;
  if (d >= DD) return;
  float a[NN], h[NN], P[NN];
#pragma unroll
  for (int n = 0; n < NN; n++){
    a[n] = -__expf(Alog[(size_t)(k * DD + d) * NN + n]);
    h[n] = 0.f; P[n] = 1.f;
  }
  const float* dtp = dt + ((size_t)(b * KK + k) * LL + chunk * CH) * DD + d;
  for (int s = 0; s < CH; s++){
    int l = chunk * CH + s;
    float dtv = dtp[(size_t)s * DD];
    float xv  = xc[((size_t)b * LL + pos_of(k, l)) * DD + d];
    float du  = dtv * xv;
#pragma unroll
    for (int n = 0; n < NN; n++){
      float e = __expf(dtv * a[n]);
      h[n] = e * h[n] + du * lB[s * NN + n];
      P[n] *= e;
    }
  }
  size_t o = ((((size_t)(b * KK + k) * NC + chunk) * DD) + d) * NN;
#pragma unroll
  for (int n = 0; n < NN; n++){ Hc[o + n] = h[n]; Pc[o + n] = P[n]; }
}

// ---------------- Kernel 4b: serial prefix over chunk summaries ----------------
// thread per (b,k,d,n) = 12288 threads
__global__ void k4b_prefix(const float* __restrict__ Hc, const float* __restrict__ Pc,
                           float* __restrict__ hin){
  int gid = blockIdx.x * 256 + threadIdx.x;
  if (gid >= BB * KK * DD * NN) return;
  int n  = gid & (NN - 1);
  int d  = (gid >> 4) % DD;
  int bk = gid / (NN * DD);
  float hv = 0.f;
  for (int c = 0; c < NC; c++){
    size_t idx = (((size_t)bk * NC + c) * DD + d) * NN + n;
    hin[idx] = hv;
    hv = Pc[idx] * hv + Hc[idx];
  }
}

// ---------------- Kernel 4c: replay chunks with true initial state, emit y ----------------
__global__ void k4c_scanC(const float* __restrict__ dt, const float* __restrict__ xc,
                          const float* __restrict__ Bsv, const float* __restrict__ Csv,
                          const float* __restrict__ Alog, const float* __restrict__ Dsv,
                          const float* __restrict__ hin, float* __restrict__ ys){
  int blk = blockIdx.x;
  int chunk = blk & (NC - 1);
  int k = (blk >> 7) & 3;
  int b = blk >> 9;
  __shared__ float lB[CH * NN];
  __shared__ float lC[CH * NN];
  {
    const float* srcB = Bsv + ((size_t)(b * KK + k) * LL + chunk * CH) * NN;
    const float* srcC = Csv + ((size_t)(b * KK + k) * LL + chunk * CH) * NN;
    for (int i = threadIdx.x; i < CH * NN; i += 128){ lB[i] = srcB[i]; lC[i] = srcC[i]; }
  }
  __syncthreads();
  int d = threadIdx.x;
  if (d >= DD) return;
  float a[NN], h[NN];
  size_t hi = (((size_t)(b * KK + k) * NC + chunk) * DD + d) * NN;
#pragma unroll
  for (int n = 0; n < NN; n++){
    a[n] = -__expf(Alog[(size_t)(k * DD + d) * NN + n]);
    h[n] = hin[hi + n];
  }
  float Dk = Dsv[k * DD + d];
  const float* dtp = dt + ((size_t)(b * KK + k) * LL + chunk * CH) * DD + d;
  float* ysp = ys + ((size_t)(b * KK + k) * LL + chunk * CH) * DD + d;
  for (int s = 0; s < CH; s++){
    int l = chunk * CH + s;
    float dtv = dtp[(size_t)s * DD];
    float xv  = xc[((size_t)b * LL + pos_of(k, l)) * DD + d];
    float du  = dtv * xv;
    float y = 0.f;
#pragma unroll
    for (int n = 0; n < NN; n++){
      float e = __expf(dtv * a[n]);
      h[n] = e * h[n] + du * lB[s * NN + n];
      y += h[n] * lC[s * NN + n];
    }
    ysp[(size_t)s * DD] = y + xv * Dk;
  }
}

// ---------------- Kernel 5: cross-merge + out-LN + gate + out_proj + residual ----------------
// one wave per pixel
__global__ void k5_merge(const float* __restrict__ ys, const float* __restrict__ z,
                         const float* __restrict__ og, const float* __restrict__ ob,
                         const float* __restrict__ opw,  // (96,96) out_proj_w[c*96+d]
                         const float* __restrict__ x, float* __restrict__ out){
  int wave = threadIdx.x >> 6, lane = threadIdx.x & 63;
  int pix = blockIdx.x * 4 + wave;
  int b = pix >> 12, pos = pix & (LL - 1);
  int h = pos >> 6, w = pos & 63;
  int lwh = (w << 6) | h;
  __shared__ float t_s[4][DD];
  const float* base = ys + (size_t)b * KK * LL * DD;

  auto gather = [&](int d) -> float {
    return base[((size_t)(0 * LL) + pos) * DD + d]
         + base[((size_t)(1 * LL) + lwh) * DD + d]
         + base[((size_t)(2 * LL) + (LL - 1 - pos)) * DD + d]
         + base[((size_t)(3 * LL) + (LL - 1 - lwh)) * DD + d];
  };
  float v0 = gather(lane);
  float v1 = (lane < 32) ? gather(64 + lane) : 0.f;
  float s  = wsum(v0 + v1);
  float sq = wsum(v0 * v0 + v1 * v1);
  float mu = s * (1.f / 96.f);
  float var = sq * (1.f / 96.f) - mu * mu;
  float rs = rsqrtf(var + 1e-5f);
  auto fin = [&](float v, int d) -> float {
    float yn = (v - mu) * rs * og[d] + ob[d];
    float zv = z[(size_t)pix * DD + d];
    return yn * siluf(zv);
  };
  t_s[wave][lane] = fin(v0, lane);
  if (lane < 32) t_s[wave][64 + lane] = fin(v1, 64 + lane);
  __syncthreads();
  const float* t = t_s[wave];
#pragma unroll
  for (int c = lane; c < CC; c += 64){
    const float* wr = opw + (size_t)c * DD;
    float acc = x[(size_t)pix * CC + c];
#pragma unroll 8
    for (int dd = 0; dd < DD; dd++) acc += t[dd] * wr[dd];
    out[(size_t)pix * CC + c] = acc;
  }
}

extern "C" void kernel_launch(void* const* d_in, const int* in_sizes, int n_in,
                              void* d_out, int out_size, void* d_ws, size_t ws_size,
                              hipStream_t stream){
  const float* x    = (const float*)d_in[0];
  const float* ng   = (const float*)d_in[1];
  const float* nb   = (const float*)d_in[2];
  const float* ipw  = (const float*)d_in[3];
  const float* cw   = (const float*)d_in[4];
  const float* cb   = (const float*)d_in[5];
  const float* xpw  = (const float*)d_in[6];
  const float* dtw  = (const float*)d_in[7];
  const float* dtb  = (const float*)d_in[8];
  const float* Alog = (const float*)d_in[9];
  const float* Dsv  = (const float*)d_in[10];
  const float* og   = (const float*)d_in[11];
  const float* ob   = (const float*)d_in[12];
  const float* opw  = (const float*)d_in[13];
  float* out = (float*)d_out;

  float* ws = (float*)d_ws;
  // workspace layout (floats)
  float* xh  = ws;                                   // B*L*D      = 786432
  float* zz  = xh  + (size_t)BB * LL * DD;           // 786432
  float* xc  = zz  + (size_t)BB * LL * DD;           // 786432
  float* dt  = xc  + (size_t)BB * LL * DD;           // B*K*L*D    = 3145728
  float* Bs  = dt  + (size_t)BB * KK * LL * DD;      // B*K*L*N    = 524288
  float* Cs  = Bs  + (size_t)BB * KK * LL * NN;      // 524288
  float* Hc  = Cs  + (size_t)BB * KK * LL * NN;      // B*K*NC*D*N = 1572864
  float* Pc  = Hc  + (size_t)BB * KK * NC * DD * NN; // 1572864
  float* hin = Pc  + (size_t)BB * KK * NC * DD * NN; // 1572864
  float* ys  = hin + (size_t)BB * KK * NC * DD * NN; // B*K*L*D    = 3145728
  // total ~ 14.4M floats = 57.7 MB

  k1_ln_inproj<<<dim3(BB * LL / 4), dim3(256), 0, stream>>>(x, ng, nb, ipw, xh, zz);
  k2_conv     <<<dim3(BB * LL * DD / 256), dim3(256), 0, stream>>>(xh, cw, cb, xc);
  k3_xproj    <<<dim3(BB * KK * LL / 4), dim3(256), 0, stream>>>(xc, xpw, dtw, dtb, dt, Bs, Cs);
  k4a_scanA   <<<dim3(BB * KK * NC), dim3(128), 0, stream>>>(dt, xc, Bs, Alog, Hc, Pc);
  k4b_prefix  <<<dim3((BB * KK * DD * NN + 255) / 256), dim3(256), 0, stream>>>(Hc, Pc, hin);
  k4c_scanC   <<<dim3(BB * KK * NC), dim3(128), 0, stream>>>(dt, xc, Bs, Cs, Alog, Dsv, hin, ys);
  k5_merge    <<<dim3(BB * LL / 4), dim3(256), 0, stream>>>(ys, zz, og, ob, opw, x, out);
}

// Round 2
// 241.969 us; speedup vs baseline: 1.0772x; 1.0772x over previous
//
#include <hip/hip_runtime.h>
#include <hip/hip_bf16.h>
#include <math.h>

// Problem constants (fixed by setup_inputs)
#define BB 2
#define HH2 64
#define WW2 64
#define CC 96
#define DD 96
#define NN 16
#define RR 6
#define KK 4
#define LL 4096           // H*W
#define CH 32             // scan chunk length
#define NC 128            // number of chunks (CH*NC == LL)

__device__ __forceinline__ float wsum(float v){
#pragma unroll
  for (int o = 32; o > 0; o >>= 1) v += __shfl_xor(v, o, 64);
  return v;
}

// map scan index l (direction k) -> spatial pixel index (h*W + w)
__device__ __forceinline__ int pos_of(int k, int l){
  int ll = (k & 2) ? (LL - 1 - l) : l;
  if (k & 1) return ((ll & 63) << 6) | (ll >> 6);   // w-major -> h*W+w
  return ll;
}

__device__ __forceinline__ float siluf(float v){ return v / (1.f + __expf(-v)); }

// ---------------- Kernel 1: pre-LN + in_proj (split xh, z) ----------------
// grid: B*L/4 blocks x 256 threads; one wave per pixel
__global__ void k1_ln_inproj(const float* __restrict__ x,
                             const float* __restrict__ g, const float* __restrict__ bta,
                             const float* __restrict__ W,   // (192,96)
                             float* __restrict__ xh, float* __restrict__ z){
  int wave = threadIdx.x >> 6, lane = threadIdx.x & 63;
  int pix  = blockIdx.x * 4 + wave;           // 0..B*L-1
  __shared__ float xn_s[4][CC];
  const float* xp = x + (size_t)pix * CC;
  float a  = xp[lane];
  float b2 = (lane < 32) ? xp[64 + lane] : 0.f;
  float s  = wsum(a + b2);
  float sq = wsum(a * a + b2 * b2);
  float mu = s * (1.f / 96.f);
  float var = sq * (1.f / 96.f) - mu * mu;
  float rs = rsqrtf(var + 1e-5f);
  xn_s[wave][lane] = (a - mu) * rs * g[lane] + bta[lane];
  if (lane < 32) xn_s[wave][64 + lane] = (b2 - mu) * rs * g[64 + lane] + bta[64 + lane];
  __syncthreads();
  const float4* xn4 = (const float4*)xn_s[wave];
#pragma unroll
  for (int j0 = 0; j0 < 3; j0++){
    int j = lane + j0 * 64;
    const float4* wr = (const float4*)(W + (size_t)j * CC);
    float a0 = 0.f, a1 = 0.f, a2 = 0.f, a3 = 0.f;
#pragma unroll
    for (int c4 = 0; c4 < 24; c4++){
      float4 w = wr[c4]; float4 xv = xn4[c4];
      a0 += w.x * xv.x; a1 += w.y * xv.y; a2 += w.z * xv.z; a3 += w.w * xv.w;
    }
    float acc = (a0 + a1) + (a2 + a3);
    if (j < DD) xh[(size_t)pix * DD + j] = acc;
    else        z [(size_t)pix * DD + (j - DD)] = acc;
  }
}

// ---------------- Kernel 2: depthwise 3x3 conv + bias + SiLU ----------------
__global__ void k2_conv(const float* __restrict__ xh,
                        const float* __restrict__ cw, const float* __restrict__ cb,
                        float* __restrict__ xc){
  int idx = blockIdx.x * 256 + threadIdx.x;
  if (idx >= BB * LL * DD) return;
  int d   = idx % DD;
  int pix = (idx / DD) % LL;
  int b   = idx / (DD * LL);
  int h = pix >> 6, w = pix & 63;
  float acc = cb[d];
#pragma unroll
  for (int kh = 0; kh < 3; kh++){
    int hh = h + kh - 1;
    if (hh < 0 || hh >= HH2) continue;
#pragma unroll
    for (int kw = 0; kw < 3; kw++){
      int ww = w + kw - 1;
      if (ww < 0 || ww >= WW2) continue;
      acc += xh[((size_t)(b * LL) + (hh * WW2 + ww)) * DD + d] * cw[d * 9 + kh * 3 + kw];
    }
  }
  xc[idx] = siluf(acc);
}

// ---------------- Kernel 3 v2: x_proj + dt_proj + softplus ----------------
// thread = pixel; weights staged in LDS (transposed), read via uniform b128 broadcast.
// grid: B*K*(L/64) = 512 blocks x 64 threads
__global__ __launch_bounds__(64) void k3_xproj(const float* __restrict__ xc,
                         const float* __restrict__ xpw,   // (K,38,96)
                         const float* __restrict__ dtw,   // (K,96,6)
                         const float* __restrict__ dtb,   // (K,96)
                         float* __restrict__ dt,          // (B,K,L,D)
                         float* __restrict__ Bsv,         // (B,K,L,N)
                         float* __restrict__ Csv){        // (B,K,L,N)
  int tid  = threadIdx.x;
  int tile = blockIdx.x & 63;
  int k    = (blockIdx.x >> 6) & 3;
  int b    = blockIdx.x >> 8;
  __shared__ float wT[96 * 40];    // wT[c*40 + r], rows 160B (16B-aligned); r=38,39 pad
  __shared__ float dtw_s[96 * 8];  // dtw_s[d*8 + r]
  __shared__ float dtb_s[96];
  const float* xpw_k = xpw + (size_t)k * 38 * 96;
  for (int i = tid; i < 38 * 96; i += 64){
    int r = i / 96, c = i - r * 96;
    wT[c * 40 + r] = xpw_k[i];
  }
  for (int i = tid; i < 576; i += 64){
    int d = i / 6, r = i - d * 6;
    dtw_s[d * 8 + r] = dtw[(size_t)k * 576 + i];
  }
  for (int i = tid; i < 96; i += 64) dtb_s[i] = dtb[k * 96 + i];
  __syncthreads();

  int l = tile * 64 + tid;
  int pos = pos_of(k, l);
  const float4* xr = (const float4*)(xc + ((size_t)b * LL + pos) * DD);

  float acc[40];
#pragma unroll
  for (int r = 0; r < 40; r++) acc[r] = 0.f;

  float4 xnext = xr[0];
#pragma unroll 4
  for (int c4 = 0; c4 < 24; c4++){
    float4 xvv = xnext;
    if (c4 < 23) xnext = xr[c4 + 1];
    float xv0 = xvv.x, xv1 = xvv.y, xv2 = xvv.z, xv3 = xvv.w;
#pragma unroll
    for (int cc = 0; cc < 4; cc++){
      float xs = (cc == 0) ? xv0 : (cc == 1) ? xv1 : (cc == 2) ? xv2 : xv3;
      const float4* wc = (const float4*)(wT + (c4 * 4 + cc) * 40);
#pragma unroll
      for (int r4 = 0; r4 < 10; r4++){
        float4 w = wc[r4];
        acc[r4 * 4 + 0] += w.x * xs;
        acc[r4 * 4 + 1] += w.y * xs;
        acc[r4 * 4 + 2] += w.z * xs;
        acc[r4 * 4 + 3] += w.w * xs;
      }
    }
  }

  size_t bkl = ((size_t)(b * KK + k) * LL + l);
  float4* Bp = (float4*)(Bsv + bkl * NN);
  Bp[0] = make_float4(acc[6],  acc[7],  acc[8],  acc[9]);
  Bp[1] = make_float4(acc[10], acc[11], acc[12], acc[13]);
  Bp[2] = make_float4(acc[14], acc[15], acc[16], acc[17]);
  Bp[3] = make_float4(acc[18], acc[19], acc[20], acc[21]);
  float4* Cp = (float4*)(Csv + bkl * NN);
  Cp[0] = make_float4(acc[22], acc[23], acc[24], acc[25]);
  Cp[1] = make_float4(acc[26], acc[27], acc[28], acc[29]);
  Cp[2] = make_float4(acc[30], acc[31], acc[32], acc[33]);
  Cp[3] = make_float4(acc[34], acc[35], acc[36], acc[37]);

  float4* dtp = (float4*)(dt + bkl * DD);
#pragma unroll 2
  for (int d4 = 0; d4 < 24; d4++){
    float4 o;
    float* op = (float*)&o;
#pragma unroll
    for (int q = 0; q < 4; q++){
      int d = d4 * 4 + q;
      float v = dtb_s[d];
#pragma unroll
      for (int r = 0; r < 6; r++) v += acc[r] * dtw_s[d * 8 + r];
      op[q] = (v > 20.f) ? v : log1pf(__expf(v));   // softplus
    }
    dtp[d4] = o;
  }
}

// ---------------- Kernel 4a: chunk-local scan (state + A-product) ----------------
__global__ void k4a_scanA(const float* __restrict__ dt, const float* __restrict__ xc,
                          const float* __restrict__ Bsv, const float* __restrict__ Alog,
                          float* __restrict__ Hc, float* __restrict__ Pc){
  int blk = blockIdx.x;
  int chunk = blk & (NC - 1);
  int k = (blk >> 7) & 3;
  int b = blk >> 9;
  __shared__ float lB[CH * NN];
  {
    const float* src = Bsv + ((size_t)(b * KK + k) * LL + chunk * CH) * NN;
    for (int i = threadIdx.x; i < CH * NN; i += 128) lB[i] = src[i];
  }
  __syncthreads();
  int d = threadIdx.x;
  if (d >= DD) return;
  float a[NN], h[NN], P[NN];
#pragma unroll
  for (int n = 0; n < NN; n++){
    a[n] = -__expf(Alog[(size_t)(k * DD + d) * NN + n]);
    h[n] = 0.f; P[n] = 1.f;
  }
  const float* dtp = dt + ((size_t)(b * KK + k) * LL + chunk * CH) * DD + d;
  for (int s = 0; s < CH; s++){
    int l = chunk * CH + s;
    float dtv = dtp[(size_t)s * DD];
    float xv  = xc[((size_t)b * LL + pos_of(k, l)) * DD + d];
    float du  = dtv * xv;
#pragma unroll
    for (int n = 0; n < NN; n++){
      float e = __expf(dtv * a[n]);
      h[n] = e * h[n] + du * lB[s * NN + n];
      P[n] *= e;
    }
  }
  size_t o = ((((size_t)(b * KK + k) * NC + chunk) * DD) + d) * NN;
#pragma unroll
  for (int n = 0; n < NN; n++){ Hc[o + n] = h[n]; Pc[o + n] = P[n]; }
}

// ---------------- Kernel 4b: serial prefix over chunk summaries ----------------
__global__ void k4b_prefix(const float* __restrict__ Hc, const float* __restrict__ Pc,
                           float* __restrict__ hin){
  int gid = blockIdx.x * 256 + threadIdx.x;
  if (gid >= BB * KK * DD * NN) return;
  int n  = gid & (NN - 1);
  int d  = (gid >> 4) % DD;
  int bk = gid / (NN * DD);
  float hv = 0.f;
  for (int c = 0; c < NC; c++){
    size_t idx = (((size_t)bk * NC + c) * DD + d) * NN + n;
    hin[idx] = hv;
    hv = Pc[idx] * hv + Hc[idx];
  }
}

// ---------------- Kernel 4c: replay chunks with true initial state, emit y ----------------
__global__ void k4c_scanC(const float* __restrict__ dt, const float* __restrict__ xc,
                          const float* __restrict__ Bsv, const float* __restrict__ Csv,
                          const float* __restrict__ Alog, const float* __restrict__ Dsv,
                          const float* __restrict__ hin, float* __restrict__ ys){
  int blk = blockIdx.x;
  int chunk = blk & (NC - 1);
  int k = (blk >> 7) & 3;
  int b = blk >> 9;
  __shared__ float lB[CH * NN];
  __shared__ float lC[CH * NN];
  {
    const float* srcB = Bsv + ((size_t)(b * KK + k) * LL + chunk * CH) * NN;
    const float* srcC = Csv + ((size_t)(b * KK + k) * LL + chunk * CH) * NN;
    for (int i = threadIdx.x; i < CH * NN; i += 128){ lB[i] = srcB[i]; lC[i] = srcC[i]; }
  }
  __syncthreads();
  int d = threadIdx.x;
  if (d >= DD) return;
  float a[NN], h[NN];
  size_t hi = (((size_t)(b * KK + k) * NC + chunk) * DD + d) * NN;
#pragma unroll
  for (int n = 0; n < NN; n++){
    a[n] = -__expf(Alog[(size_t)(k * DD + d) * NN + n]);
    h[n] = hin[hi + n];
  }
  float Dk = Dsv[k * DD + d];
  const float* dtp = dt + ((size_t)(b * KK + k) * LL + chunk * CH) * DD + d;
  float* ysp = ys + ((size_t)(b * KK + k) * LL + chunk * CH) * DD + d;
  for (int s = 0; s < CH; s++){
    int l = chunk * CH + s;
    float dtv = dtp[(size_t)s * DD];
    float xv  = xc[((size_t)b * LL + pos_of(k, l)) * DD + d];
    float du  = dtv * xv;
    float y = 0.f;
#pragma unroll
    for (int n = 0; n < NN; n++){
      float e = __expf(dtv * a[n]);
      h[n] = e * h[n] + du * lB[s * NN + n];
      y += h[n] * lC[s * NN + n];
    }
    ysp[(size_t)s * DD] = y + xv * Dk;
  }
}

// ---------------- Kernel 5: cross-merge + out-LN + gate + out_proj + residual ----------------
__global__ void k5_merge(const float* __restrict__ ys, const float* __restrict__ z,
                         const float* __restrict__ og, const float* __restrict__ ob,
                         const float* __restrict__ opw,  // (96,96)
                         const float* __restrict__ x, float* __restrict__ out){
  int wave = threadIdx.x >> 6, lane = threadIdx.x & 63;
  int pix = blockIdx.x * 4 + wave;
  int b = pix >> 12, pos = pix & (LL - 1);
  int h = pos >> 6, w = pos & 63;
  int lwh = (w << 6) | h;
  __shared__ float t_s[4][DD];
  const float* base = ys + (size_t)b * KK * LL * DD;

  auto gather = [&](int d) -> float {
    return base[((size_t)(0 * LL) + pos) * DD + d]
         + base[((size_t)(1 * LL) + lwh) * DD + d]
         + base[((size_t)(2 * LL) + (LL - 1 - pos)) * DD + d]
         + base[((size_t)(3 * LL) + (LL - 1 - lwh)) * DD + d];
  };
  float v0 = gather(lane);
  float v1 = (lane < 32) ? gather(64 + lane) : 0.f;
  float s  = wsum(v0 + v1);
  float sq = wsum(v0 * v0 + v1 * v1);
  float mu = s * (1.f / 96.f);
  float var = sq * (1.f / 96.f) - mu * mu;
  float rs = rsqrtf(var + 1e-5f);
  auto fin = [&](float v, int d) -> float {
    float yn = (v - mu) * rs * og[d] + ob[d];
    float zv = z[(size_t)pix * DD + d];
    return yn * siluf(zv);
  };
  t_s[wave][lane] = fin(v0, lane);
  if (lane < 32) t_s[wave][64 + lane] = fin(v1, 64 + lane);
  __syncthreads();
  const float4* t4 = (const float4*)t_s[wave];
#pragma unroll
  for (int c = lane; c < CC; c += 64){
    const float4* wr = (const float4*)(opw + (size_t)c * DD);
    float a0 = 0.f, a1 = 0.f, a2 = 0.f, a3 = 0.f;
#pragma unroll
    for (int c4 = 0; c4 < 24; c4++){
      float4 w = wr[c4]; float4 tv = t4[c4];
      a0 += w.x * tv.x; a1 += w.y * tv.y; a2 += w.z * tv.z; a3 += w.w * tv.w;
    }
    out[(size_t)pix * CC + c] = x[(size_t)pix * CC + c] + (a0 + a1) + (a2 + a3);
  }
}

extern "C" void kernel_launch(void* const* d_in, const int* in_sizes, int n_in,
                              void* d_out, int out_size, void* d_ws, size_t ws_size,
                              hipStream_t stream){
  const float* x    = (const float*)d_in[0];
  const float* ng   = (const float*)d_in[1];
  const float* nb   = (const float*)d_in[2];
  const float* ipw  = (const float*)d_in[3];
  const float* cw   = (const float*)d_in[4];
  const float* cb   = (const float*)d_in[5];
  const float* xpw  = (const float*)d_in[6];
  const float* dtw  = (const float*)d_in[7];
  const float* dtb  = (const float*)d_in[8];
  const float* Alog = (const float*)d_in[9];
  const float* Dsv  = (const float*)d_in[10];
  const float* og   = (const float*)d_in[11];
  const float* ob   = (const float*)d_in[12];
  const float* opw  = (const float*)d_in[13];
  float* out = (float*)d_out;

  float* ws = (float*)d_ws;
  float* xh  = ws;
  float* zz  = xh  + (size_t)BB * LL * DD;
  float* xc  = zz  + (size_t)BB * LL * DD;
  float* dt  = xc  + (size_t)BB * LL * DD;
  float* Bs  = dt  + (size_t)BB * KK * LL * DD;
  float* Cs  = Bs  + (size_t)BB * KK * LL * NN;
  float* Hc  = Cs  + (size_t)BB * KK * LL * NN;
  float* Pc  = Hc  + (size_t)BB * KK * NC * DD * NN;
  float* hin = Pc  + (size_t)BB * KK * NC * DD * NN;
  float* ys  = hin + (size_t)BB * KK * NC * DD * NN;

  k1_ln_inproj<<<dim3(BB * LL / 4), dim3(256), 0, stream>>>(x, ng, nb, ipw, xh, zz);
  k2_conv     <<<dim3(BB * LL * DD / 256), dim3(256), 0, stream>>>(xh, cw, cb, xc);
  k3_xproj    <<<dim3(BB * KK * LL / 64), dim3(64), 0, stream>>>(xc, xpw, dtw, dtb, dt, Bs, Cs);
  k4a_scanA   <<<dim3(BB * KK * NC), dim3(128), 0, stream>>>(dt, xc, Bs, Alog, Hc, Pc);
  k4b_prefix  <<<dim3((BB * KK * DD * NN + 255) / 256), dim3(256), 0, stream>>>(Hc, Pc, hin);
  k4c_scanC   <<<dim3(BB * KK * NC), dim3(128), 0, stream>>>(dt, xc, Bs, Cs, Alog, Dsv, hin, ys);
  k5_merge    <<<dim3(BB * LL / 4), dim3(256), 0, stream>>>(ys, zz, og, ob, opw, x, out);
}

// Round 3
// 173.136 us; speedup vs baseline: 1.5054x; 1.3976x over previous
//
#include <hip/hip_runtime.h>
#include <hip/hip_bf16.h>
#include <math.h>

// Problem constants (fixed by setup_inputs)
#define BB 2
#define HH2 64
#define WW2 64
#define CC 96
#define DD 96
#define NN 16
#define RR 6
#define KK 4
#define LL 4096           // H*W
#define CH 32             // scan chunk length
#define NC 128            // number of chunks (CH*NC == LL)

__device__ __forceinline__ float wsum(float v){
#pragma unroll
  for (int o = 32; o > 0; o >>= 1) v += __shfl_xor(v, o, 64);
  return v;
}

// map scan index l (direction k) -> spatial pixel index (h*W + w)
__device__ __forceinline__ int pos_of(int k, int l){
  int ll = (k & 2) ? (LL - 1 - l) : l;
  if (k & 1) return ((ll & 63) << 6) | (ll >> 6);   // w-major -> h*W+w
  return ll;
}

__device__ __forceinline__ float siluf(float v){ return v / (1.f + __expf(-v)); }

// ---------------- Kernel 1 v3: pre-LN + in_proj, k3-style ----------------
// thread = pixel; 24-row weight chunk staged transposed in LDS, uniform b128 reads.
// grid: 8 chunks x 32 tiles = 256 blocks x 256 threads
__global__ __launch_bounds__(256) void k1_ln_inproj(const float* __restrict__ x,
                             const float* __restrict__ g, const float* __restrict__ bta,
                             const float* __restrict__ W,   // (192,96)
                             float* __restrict__ xh, float* __restrict__ z){
  int tid   = threadIdx.x;
  int tile  = blockIdx.x & 31;    // 32 tiles of 256 pixels
  int chunk = blockIdx.x >> 5;    // 0..7 -> rows [chunk*24, chunk*24+24)
  __shared__ float wT[96][24];    // transposed chunk
  __shared__ float g_s[96], b_s[96];
  const float* Wc = W + (size_t)chunk * 24 * 96;
  for (int i = tid; i < 24 * 96; i += 256){
    int r = i / 96, c = i - r * 96;
    wT[c][r] = Wc[i];
  }
  if (tid < 96) g_s[tid] = g[tid];
  else if (tid < 192) b_s[tid - 96] = bta[tid - 96];
  __syncthreads();

  int pix = tile * 256 + tid;     // 0..B*L-1
  const float4* xr = (const float4*)(x + (size_t)pix * CC);
  // pass 1: mean / var
  float s = 0.f, sq = 0.f;
#pragma unroll
  for (int c4 = 0; c4 < 24; c4++){
    float4 v = xr[c4];
    s  += (v.x + v.y) + (v.z + v.w);
    sq += (v.x * v.x + v.y * v.y) + (v.z * v.z + v.w * v.w);
  }
  float mu = s * (1.f / 96.f);
  float rs = rsqrtf(sq * (1.f / 96.f) - mu * mu + 1e-5f);

  float acc[24];
#pragma unroll
  for (int r = 0; r < 24; r++) acc[r] = 0.f;

  const float4* g4 = (const float4*)g_s;
  const float4* b4 = (const float4*)b_s;
#pragma unroll 4
  for (int c4 = 0; c4 < 24; c4++){
    float4 xv = xr[c4];
    float4 gv = g4[c4], bv = b4[c4];
    float xn[4];
    xn[0] = (xv.x - mu) * rs * gv.x + bv.x;
    xn[1] = (xv.y - mu) * rs * gv.y + bv.y;
    xn[2] = (xv.z - mu) * rs * gv.z + bv.z;
    xn[3] = (xv.w - mu) * rs * gv.w + bv.w;
#pragma unroll
    for (int cc = 0; cc < 4; cc++){
      const float4* wc = (const float4*)wT[c4 * 4 + cc];
      float xs = xn[cc];
#pragma unroll
      for (int r4 = 0; r4 < 6; r4++){
        float4 w = wc[r4];
        acc[r4 * 4 + 0] += w.x * xs;
        acc[r4 * 4 + 1] += w.y * xs;
        acc[r4 * 4 + 2] += w.z * xs;
        acc[r4 * 4 + 3] += w.w * xs;
      }
    }
  }
  float* dst = (chunk < 4 ? xh : z) + (size_t)pix * DD + (chunk & 3) * 24;
  float4* dp = (float4*)dst;
#pragma unroll
  for (int r4 = 0; r4 < 6; r4++)
    dp[r4] = make_float4(acc[r4 * 4], acc[r4 * 4 + 1], acc[r4 * 4 + 2], acc[r4 * 4 + 3]);
}

// ---------------- Kernel 2: depthwise 3x3 conv + bias + SiLU ----------------
__global__ void k2_conv(const float* __restrict__ xh,
                        const float* __restrict__ cw, const float* __restrict__ cb,
                        float* __restrict__ xc){
  int idx = blockIdx.x * 256 + threadIdx.x;
  if (idx >= BB * LL * DD) return;
  int d   = idx % DD;
  int pix = (idx / DD) % LL;
  int b   = idx / (DD * LL);
  int h = pix >> 6, w = pix & 63;
  float acc = cb[d];
#pragma unroll
  for (int kh = 0; kh < 3; kh++){
    int hh = h + kh - 1;
    if (hh < 0 || hh >= HH2) continue;
#pragma unroll
    for (int kw = 0; kw < 3; kw++){
      int ww = w + kw - 1;
      if (ww < 0 || ww >= WW2) continue;
      acc += xh[((size_t)(b * LL) + (hh * WW2 + ww)) * DD + d] * cw[d * 9 + kh * 3 + kw];
    }
  }
  xc[idx] = siluf(acc);
}

// ---------------- Kernel 3 v2: x_proj + dt_proj + softplus ----------------
__global__ __launch_bounds__(64) void k3_xproj(const float* __restrict__ xc,
                         const float* __restrict__ xpw,   // (K,38,96)
                         const float* __restrict__ dtw,   // (K,96,6)
                         const float* __restrict__ dtb,   // (K,96)
                         float* __restrict__ dt,          // (B,K,L,D)
                         float* __restrict__ Bsv,         // (B,K,L,N)
                         float* __restrict__ Csv){        // (B,K,L,N)
  int tid  = threadIdx.x;
  int tile = blockIdx.x & 63;
  int k    = (blockIdx.x >> 6) & 3;
  int b    = blockIdx.x >> 8;
  __shared__ float wT[96 * 40];    // wT[c*40 + r]
  __shared__ float dtw_s[96 * 8];
  __shared__ float dtb_s[96];
  const float* xpw_k = xpw + (size_t)k * 38 * 96;
  for (int i = tid; i < 38 * 96; i += 64){
    int r = i / 96, c = i - r * 96;
    wT[c * 40 + r] = xpw_k[i];
  }
  for (int i = tid; i < 576; i += 64){
    int d = i / 6, r = i - d * 6;
    dtw_s[d * 8 + r] = dtw[(size_t)k * 576 + i];
  }
  for (int i = tid; i < 96; i += 64) dtb_s[i] = dtb[k * 96 + i];
  __syncthreads();

  int l = tile * 64 + tid;
  int pos = pos_of(k, l);
  const float4* xr = (const float4*)(xc + ((size_t)b * LL + pos) * DD);

  float acc[40];
#pragma unroll
  for (int r = 0; r < 40; r++) acc[r] = 0.f;

  float4 xnext = xr[0];
#pragma unroll 4
  for (int c4 = 0; c4 < 24; c4++){
    float4 xvv = xnext;
    if (c4 < 23) xnext = xr[c4 + 1];
    float xn[4] = {xvv.x, xvv.y, xvv.z, xvv.w};
#pragma unroll
    for (int cc = 0; cc < 4; cc++){
      float xs = xn[cc];
      const float4* wc = (const float4*)(wT + (c4 * 4 + cc) * 40);
#pragma unroll
      for (int r4 = 0; r4 < 10; r4++){
        float4 w = wc[r4];
        acc[r4 * 4 + 0] += w.x * xs;
        acc[r4 * 4 + 1] += w.y * xs;
        acc[r4 * 4 + 2] += w.z * xs;
        acc[r4 * 4 + 3] += w.w * xs;
      }
    }
  }

  size_t bkl = ((size_t)(b * KK + k) * LL + l);
  float4* Bp = (float4*)(Bsv + bkl * NN);
  Bp[0] = make_float4(acc[6],  acc[7],  acc[8],  acc[9]);
  Bp[1] = make_float4(acc[10], acc[11], acc[12], acc[13]);
  Bp[2] = make_float4(acc[14], acc[15], acc[16], acc[17]);
  Bp[3] = make_float4(acc[18], acc[19], acc[20], acc[21]);
  float4* Cp = (float4*)(Csv + bkl * NN);
  Cp[0] = make_float4(acc[22], acc[23], acc[24], acc[25]);
  Cp[1] = make_float4(acc[26], acc[27], acc[28], acc[29]);
  Cp[2] = make_float4(acc[30], acc[31], acc[32], acc[33]);
  Cp[3] = make_float4(acc[34], acc[35], acc[36], acc[37]);

  float4* dtp = (float4*)(dt + bkl * DD);
#pragma unroll 2
  for (int d4 = 0; d4 < 24; d4++){
    float4 o;
    float* op = (float*)&o;
#pragma unroll
    for (int q = 0; q < 4; q++){
      int d = d4 * 4 + q;
      float v = dtb_s[d];
#pragma unroll
      for (int r = 0; r < 6; r++) v += acc[r] * dtw_s[d * 8 + r];
      op[q] = (v > 20.f) ? v : log1pf(__expf(v));   // softplus
    }
    dtp[d4] = o;
  }
}

// ---------------- Kernel 4a: chunk-local scan (state + A-product) ----------------
__global__ void k4a_scanA(const float* __restrict__ dt, const float* __restrict__ xc,
                          const float* __restrict__ Bsv, const float* __restrict__ Alog,
                          float* __restrict__ Hc, float* __restrict__ Pc){
  int blk = blockIdx.x;
  int chunk = blk & (NC - 1);
  int k = (blk >> 7) & 3;
  int b = blk >> 9;
  __shared__ float lB[CH * NN];
  {
    const float* src = Bsv + ((size_t)(b * KK + k) * LL + chunk * CH) * NN;
    for (int i = threadIdx.x; i < CH * NN; i += 128) lB[i] = src[i];
  }
  __syncthreads();
  int d = threadIdx.x;
  if (d >= DD) return;
  float a[NN], h[NN], P[NN];
#pragma unroll
  for (int n = 0; n < NN; n++){
    a[n] = -__expf(Alog[(size_t)(k * DD + d) * NN + n]);
    h[n] = 0.f; P[n] = 1.f;
  }
  const float* dtp = dt + ((size_t)(b * KK + k) * LL + chunk * CH) * DD + d;
  for (int s = 0; s < CH; s++){
    int l = chunk * CH + s;
    float dtv = dtp[(size_t)s * DD];
    float xv  = xc[((size_t)b * LL + pos_of(k, l)) * DD + d];
    float du  = dtv * xv;
#pragma unroll
    for (int n = 0; n < NN; n++){
      float e = __expf(dtv * a[n]);
      h[n] = e * h[n] + du * lB[s * NN + n];
      P[n] *= e;
    }
  }
  size_t o = ((((size_t)(b * KK + k) * NC + chunk) * DD) + d) * NN;
#pragma unroll
  for (int n = 0; n < NN; n++){ Hc[o + n] = h[n]; Pc[o + n] = P[n]; }
}

// ---------------- Kernel 4b: serial prefix over chunk summaries ----------------
__global__ void k4b_prefix(const float* __restrict__ Hc, const float* __restrict__ Pc,
                           float* __restrict__ hin){
  int gid = blockIdx.x * 256 + threadIdx.x;
  if (gid >= BB * KK * DD * NN) return;
  int n  = gid & (NN - 1);
  int d  = (gid >> 4) % DD;
  int bk = gid / (NN * DD);
  float hv = 0.f;
  for (int c = 0; c < NC; c++){
    size_t idx = (((size_t)bk * NC + c) * DD + d) * NN + n;
    hin[idx] = hv;
    hv = Pc[idx] * hv + Hc[idx];
  }
}

// ---------------- Kernel 4c: replay chunks with true initial state, emit y ----------------
__global__ void k4c_scanC(const float* __restrict__ dt, const float* __restrict__ xc,
                          const float* __restrict__ Bsv, const float* __restrict__ Csv,
                          const float* __restrict__ Alog, const float* __restrict__ Dsv,
                          const float* __restrict__ hin, float* __restrict__ ys){
  int blk = blockIdx.x;
  int chunk = blk & (NC - 1);
  int k = (blk >> 7) & 3;
  int b = blk >> 9;
  __shared__ float lB[CH * NN];
  __shared__ float lC[CH * NN];
  {
    const float* srcB = Bsv + ((size_t)(b * KK + k) * LL + chunk * CH) * NN;
    const float* srcC = Csv + ((size_t)(b * KK + k) * LL + chunk * CH) * NN;
    for (int i = threadIdx.x; i < CH * NN; i += 128){ lB[i] = srcB[i]; lC[i] = srcC[i]; }
  }
  __syncthreads();
  int d = threadIdx.x;
  if (d >= DD) return;
  float a[NN], h[NN];
  size_t hi = (((size_t)(b * KK + k) * NC + chunk) * DD + d) * NN;
#pragma unroll
  for (int n = 0; n < NN; n++){
    a[n] = -__expf(Alog[(size_t)(k * DD + d) * NN + n]);
    h[n] = hin[hi + n];
  }
  float Dk = Dsv[k * DD + d];
  const float* dtp = dt + ((size_t)(b * KK + k) * LL + chunk * CH) * DD + d;
  float* ysp = ys + ((size_t)(b * KK + k) * LL + chunk * CH) * DD + d;
  for (int s = 0; s < CH; s++){
    int l = chunk * CH + s;
    float dtv = dtp[(size_t)s * DD];
    float xv  = xc[((size_t)b * LL + pos_of(k, l)) * DD + d];
    float du  = dtv * xv;
    float y = 0.f;
#pragma unroll
    for (int n = 0; n < NN; n++){
      float e = __expf(dtv * a[n]);
      h[n] = e * h[n] + du * lB[s * NN + n];
      y += h[n] * lC[s * NN + n];
    }
    ysp[(size_t)s * DD] = y + xv * Dk;
  }
}

// ---------------- Kernel 5a: cross-merge + out-LN + gate -> t ----------------
// one wave per pixel (coalesced gathers); no weight reads
__global__ void k5a_merge(const float* __restrict__ ys, const float* __restrict__ z,
                          const float* __restrict__ og, const float* __restrict__ ob,
                          float* __restrict__ t){
  int wave = threadIdx.x >> 6, lane = threadIdx.x & 63;
  int pix = blockIdx.x * 4 + wave;
  int b = pix >> 12, pos = pix & (LL - 1);
  int h = pos >> 6, w = pos & 63;
  int lwh = (w << 6) | h;
  const float* base = ys + (size_t)b * KK * LL * DD;

  auto gather = [&](int d) -> float {
    return base[((size_t)(0 * LL) + pos) * DD + d]
         + base[((size_t)(1 * LL) + lwh) * DD + d]
         + base[((size_t)(2 * LL) + (LL - 1 - pos)) * DD + d]
         + base[((size_t)(3 * LL) + (LL - 1 - lwh)) * DD + d];
  };
  float v0 = gather(lane);
  float v1 = (lane < 32) ? gather(64 + lane) : 0.f;
  float s  = wsum(v0 + v1);
  float sq = wsum(v0 * v0 + v1 * v1);
  float mu = s * (1.f / 96.f);
  float var = sq * (1.f / 96.f) - mu * mu;
  float rs = rsqrtf(var + 1e-5f);
  auto fin = [&](float v, int d) -> float {
    float yn = (v - mu) * rs * og[d] + ob[d];
    float zv = z[(size_t)pix * DD + d];
    return yn * siluf(zv);
  };
  t[(size_t)pix * DD + lane] = fin(v0, lane);
  if (lane < 32) t[(size_t)pix * DD + 64 + lane] = fin(v1, 64 + lane);
}

// ---------------- Kernel 5b: out_proj + residual, k3-style ----------------
// grid: 4 chunks x 128 tiles = 512 blocks x 64 threads
__global__ __launch_bounds__(64) void k5b_outproj(const float* __restrict__ t,
                          const float* __restrict__ opw,  // (96,96)
                          const float* __restrict__ x, float* __restrict__ out){
  int tid   = threadIdx.x;
  int tile  = blockIdx.x & 127;   // 128 tiles of 64 pixels
  int chunk = blockIdx.x >> 7;    // 0..3 -> rows [chunk*24, +24)
  __shared__ float wT[96][24];
  const float* Wc = opw + (size_t)chunk * 24 * 96;
  for (int i = tid; i < 24 * 96; i += 64){
    int r = i / 96, c = i - r * 96;
    wT[c][r] = Wc[i];
  }
  __syncthreads();
  int pix = tile * 64 + tid;
  const float4* tr = (const float4*)(t + (size_t)pix * DD);
  float acc[24];
#pragma unroll
  for (int r = 0; r < 24; r++) acc[r] = 0.f;
#pragma unroll 4
  for (int c4 = 0; c4 < 24; c4++){
    float4 tv = tr[c4];
    float xn[4] = {tv.x, tv.y, tv.z, tv.w};
#pragma unroll
    for (int cc = 0; cc < 4; cc++){
      const float4* wc = (const float4*)wT[c4 * 4 + cc];
      float xs = xn[cc];
#pragma unroll
      for (int r4 = 0; r4 < 6; r4++){
        float4 w = wc[r4];
        acc[r4 * 4 + 0] += w.x * xs;
        acc[r4 * 4 + 1] += w.y * xs;
        acc[r4 * 4 + 2] += w.z * xs;
        acc[r4 * 4 + 3] += w.w * xs;
      }
    }
  }
  const float4* xr = (const float4*)(x + (size_t)pix * CC + chunk * 24);
  float4* op = (float4*)(out + (size_t)pix * CC + chunk * 24);
#pragma unroll
  for (int r4 = 0; r4 < 6; r4++){
    float4 xv = xr[r4];
    op[r4] = make_float4(xv.x + acc[r4 * 4], xv.y + acc[r4 * 4 + 1],
                         xv.z + acc[r4 * 4 + 2], xv.w + acc[r4 * 4 + 3]);
  }
}

extern "C" void kernel_launch(void* const* d_in, const int* in_sizes, int n_in,
                              void* d_out, int out_size, void* d_ws, size_t ws_size,
                              hipStream_t stream){
  const float* x    = (const float*)d_in[0];
  const float* ng   = (const float*)d_in[1];
  const float* nb   = (const float*)d_in[2];
  const float* ipw  = (const float*)d_in[3];
  const float* cw   = (const float*)d_in[4];
  const float* cb   = (const float*)d_in[5];
  const float* xpw  = (const float*)d_in[6];
  const float* dtw  = (const float*)d_in[7];
  const float* dtb  = (const float*)d_in[8];
  const float* Alog = (const float*)d_in[9];
  const float* Dsv  = (const float*)d_in[10];
  const float* og   = (const float*)d_in[11];
  const float* ob   = (const float*)d_in[12];
  const float* opw  = (const float*)d_in[13];
  float* out = (float*)d_out;

  float* ws = (float*)d_ws;
  float* xh  = ws;
  float* zz  = xh  + (size_t)BB * LL * DD;
  float* xc  = zz  + (size_t)BB * LL * DD;
  float* dt  = xc  + (size_t)BB * LL * DD;
  float* Bs  = dt  + (size_t)BB * KK * LL * DD;
  float* Cs  = Bs  + (size_t)BB * KK * LL * NN;
  float* Hc  = Cs  + (size_t)BB * KK * LL * NN;
  float* Pc  = Hc  + (size_t)BB * KK * NC * DD * NN;
  float* hin = Pc  + (size_t)BB * KK * NC * DD * NN;
  float* ys  = hin + (size_t)BB * KK * NC * DD * NN;
  float* t   = xh;   // xh is dead after k2; reuse as gated-LN buffer

  k1_ln_inproj<<<dim3(256), dim3(256), 0, stream>>>(x, ng, nb, ipw, xh, zz);
  k2_conv     <<<dim3(BB * LL * DD / 256), dim3(256), 0, stream>>>(xh, cw, cb, xc);
  k3_xproj    <<<dim3(BB * KK * LL / 64), dim3(64), 0, stream>>>(xc, xpw, dtw, dtb, dt, Bs, Cs);
  k4a_scanA   <<<dim3(BB * KK * NC), dim3(128), 0, stream>>>(dt, xc, Bs, Alog, Hc, Pc);
  k4b_prefix  <<<dim3((BB * KK * DD * NN + 255) / 256), dim3(256), 0, stream>>>(Hc, Pc, hin);
  k4c_scanC   <<<dim3(BB * KK * NC), dim3(128), 0, stream>>>(dt, xc, Bs, Cs, Alog, Dsv, hin, ys);
  k5a_merge   <<<dim3(BB * LL / 4), dim3(256), 0, stream>>>(ys, zz, og, ob, t);
  k5b_outproj <<<dim3(512), dim3(64), 0, stream>>>(t, opw, x, out);
}

// Round 4
// 159.309 us; speedup vs baseline: 1.6361x; 1.0868x over previous
//
#include <hip/hip_runtime.h>
#include <hip/hip_bf16.h>
#include <math.h>

// Problem constants (fixed by setup_inputs)
#define BB 2
#define HH2 64
#define WW2 64
#define CC 96
#define DD 96
#define NN 16
#define RR 6
#define KK 4
#define LL 4096           // H*W
#define CH 32             // scan chunk length
#define NC 128            // number of chunks (CH*NC == LL)

__device__ __forceinline__ float wsum(float v){
#pragma unroll
  for (int o = 32; o > 0; o >>= 1) v += __shfl_xor(v, o, 64);
  return v;
}

// map scan index l (direction k) -> spatial pixel index (h*W + w)
__device__ __forceinline__ int pos_of(int k, int l){
  int ll = (k & 2) ? (LL - 1 - l) : l;
  if (k & 1) return ((ll & 63) << 6) | (ll >> 6);   // w-major -> h*W+w
  return ll;
}

// inverse: spatial pixel p -> scan index l for direction k
__device__ __forceinline__ int inv_pos(int k, int p){
  int t = ((p & 63) << 6) | (p >> 6);
  switch (k & 3){
    case 0: return p;
    case 1: return t;
    case 2: return LL - 1 - p;
    default: return LL - 1 - t;
  }
}

__device__ __forceinline__ float siluf(float v){ return v / (1.f + __expf(-v)); }

// ---------------- Kernel 1 v3: pre-LN + in_proj, LDS-broadcast GEMV ----------------
// grid: 8 chunks x 32 tiles = 256 blocks x 256 threads
__global__ __launch_bounds__(256) void k1_ln_inproj(const float* __restrict__ x,
                             const float* __restrict__ g, const float* __restrict__ bta,
                             const float* __restrict__ W,   // (192,96)
                             float* __restrict__ xh, float* __restrict__ z){
  int tid   = threadIdx.x;
  int tile  = blockIdx.x & 31;    // 32 tiles of 256 pixels
  int chunk = blockIdx.x >> 5;    // 0..7 -> rows [chunk*24, chunk*24+24)
  __shared__ float wT[96][24];    // transposed chunk
  __shared__ float g_s[96], b_s[96];
  const float* Wc = W + (size_t)chunk * 24 * 96;
  for (int i = tid; i < 24 * 96; i += 256){
    int c = i / 24, r = i - c * 24;     // consecutive i -> consecutive LDS addr
    wT[c][r] = Wc[r * 96 + c];
  }
  if (tid < 96) g_s[tid] = g[tid];
  else if (tid < 192) b_s[tid - 96] = bta[tid - 96];
  __syncthreads();

  int pix = tile * 256 + tid;     // 0..B*L-1
  const float4* xr = (const float4*)(x + (size_t)pix * CC);
  float s = 0.f, sq = 0.f;
#pragma unroll
  for (int c4 = 0; c4 < 24; c4++){
    float4 v = xr[c4];
    s  += (v.x + v.y) + (v.z + v.w);
    sq += (v.x * v.x + v.y * v.y) + (v.z * v.z + v.w * v.w);
  }
  float mu = s * (1.f / 96.f);
  float rs = rsqrtf(sq * (1.f / 96.f) - mu * mu + 1e-5f);

  float acc[24];
#pragma unroll
  for (int r = 0; r < 24; r++) acc[r] = 0.f;

  const float4* g4 = (const float4*)g_s;
  const float4* b4 = (const float4*)b_s;
#pragma unroll 4
  for (int c4 = 0; c4 < 24; c4++){
    float4 xv = xr[c4];
    float4 gv = g4[c4], bv = b4[c4];
    float xn[4];
    xn[0] = (xv.x - mu) * rs * gv.x + bv.x;
    xn[1] = (xv.y - mu) * rs * gv.y + bv.y;
    xn[2] = (xv.z - mu) * rs * gv.z + bv.z;
    xn[3] = (xv.w - mu) * rs * gv.w + bv.w;
#pragma unroll
    for (int cc = 0; cc < 4; cc++){
      const float4* wc = (const float4*)wT[c4 * 4 + cc];
      float xs = xn[cc];
#pragma unroll
      for (int r4 = 0; r4 < 6; r4++){
        float4 w = wc[r4];
        acc[r4 * 4 + 0] += w.x * xs;
        acc[r4 * 4 + 1] += w.y * xs;
        acc[r4 * 4 + 2] += w.z * xs;
        acc[r4 * 4 + 3] += w.w * xs;
      }
    }
  }
  float* dst = (chunk < 4 ? xh : z) + (size_t)pix * DD + (chunk & 3) * 24;
  float4* dp = (float4*)dst;
#pragma unroll
  for (int r4 = 0; r4 < 6; r4++)
    dp[r4] = make_float4(acc[r4 * 4], acc[r4 * 4 + 1], acc[r4 * 4 + 2], acc[r4 * 4 + 3]);
}

// ---------------- Kernel 2: depthwise 3x3 conv + bias + SiLU ----------------
__global__ void k2_conv(const float* __restrict__ xh,
                        const float* __restrict__ cw, const float* __restrict__ cb,
                        float* __restrict__ xc){
  int idx = blockIdx.x * 256 + threadIdx.x;
  if (idx >= BB * LL * DD) return;
  int d   = idx % DD;
  int pix = (idx / DD) % LL;
  int b   = idx / (DD * LL);
  int h = pix >> 6, w = pix & 63;
  float acc = cb[d];
#pragma unroll
  for (int kh = 0; kh < 3; kh++){
    int hh = h + kh - 1;
    if (hh < 0 || hh >= HH2) continue;
#pragma unroll
    for (int kw = 0; kw < 3; kw++){
      int ww = w + kw - 1;
      if (ww < 0 || ww >= WW2) continue;
      acc += xh[((size_t)(b * LL) + (hh * WW2 + ww)) * DD + d] * cw[d * 9 + kh * 3 + kw];
    }
  }
  xc[idx] = siluf(acc);
}

// ---------------- Kernel 3 v3: x_proj + dt_proj, pixel-ordered, chunked ----------------
// grid: 12 (k,part) x 64 tiles = 768 blocks x 128 threads
// part 0: dt rows (0..5) + dt_proj + softplus -> dt
// part 1: B rows (6..21) -> Bs ; part 2: C rows (22..37) -> Cs
__global__ __launch_bounds__(128) void k3_xproj(const float* __restrict__ xc,
                         const float* __restrict__ xpw,   // (K,38,96)
                         const float* __restrict__ dtw,   // (K,96,6)
                         const float* __restrict__ dtb,   // (K,96)
                         float* __restrict__ dt,          // (B,K,L,D)
                         float* __restrict__ Bsv,         // (B,K,L,N)
                         float* __restrict__ Csv){        // (B,K,L,N)
  int tid  = threadIdx.x;
  int tile = blockIdx.x & 63;       // 64 tiles of 128 pixels
  int kp   = blockIdx.x >> 6;       // 0..11
  int k    = kp & 3;
  int part = kp >> 2;               // 0..2

  __shared__ float wT[96][16];      // transposed weight chunk (rows 16-padded)
  __shared__ float dtw_s[96 * 8];
  __shared__ float dtb_s[96];

  const float* xpw_k = xpw + (size_t)k * 38 * 96;
  if (part == 0){
    for (int i = tid; i < 96 * 16; i += 128){
      int c = i >> 4, r = i & 15;
      wT[c][r] = (r < RR) ? xpw_k[r * 96 + c] : 0.f;
    }
    for (int i = tid; i < 96 * 8; i += 128){
      int d = i >> 3, r = i & 7;
      dtw_s[i] = (r < RR) ? dtw[(size_t)k * 576 + d * 6 + r] : 0.f;
    }
    if (tid < 96) dtb_s[tid] = dtb[k * 96 + tid];
  } else {
    int rbase = 6 + (part - 1) * 16;
    for (int i = tid; i < 96 * 16; i += 128){
      int c = i >> 4, r = i & 15;
      wT[c][r] = xpw_k[(rbase + r) * 96 + c];
    }
  }
  __syncthreads();

  int gpix = tile * 128 + tid;      // 0..B*L-1
  int b = gpix >> 12, p = gpix & (LL - 1);
  int l = inv_pos(k, p);
  size_t bkl = ((size_t)(b * KK + k) * LL + l);
  const float4* xr = (const float4*)(xc + (size_t)gpix * DD);

  if (part == 0){
    float acc[8];
#pragma unroll
    for (int r = 0; r < 8; r++) acc[r] = 0.f;
#pragma unroll 4
    for (int c4 = 0; c4 < 24; c4++){
      float4 xv = xr[c4];
      float xn[4] = {xv.x, xv.y, xv.z, xv.w};
#pragma unroll
      for (int cc = 0; cc < 4; cc++){
        const float4* wc = (const float4*)wT[c4 * 4 + cc];
        float xs = xn[cc];
        float4 w0 = wc[0], w1 = wc[1];
        acc[0] += w0.x * xs; acc[1] += w0.y * xs;
        acc[2] += w0.z * xs; acc[3] += w0.w * xs;
        acc[4] += w1.x * xs; acc[5] += w1.y * xs;
      }
    }
    float4* dtp = (float4*)(dt + bkl * DD);
#pragma unroll 2
    for (int d4 = 0; d4 < 24; d4++){
      float4 o;
      float* op = (float*)&o;
#pragma unroll
      for (int q = 0; q < 4; q++){
        int d = d4 * 4 + q;
        const float4* wr = (const float4*)(dtw_s + d * 8);
        float4 w0 = wr[0], w1 = wr[1];
        float v = dtb_s[d] + acc[0] * w0.x + acc[1] * w0.y + acc[2] * w0.z
                + acc[3] * w0.w + acc[4] * w1.x + acc[5] * w1.y;
        op[q] = (v > 20.f) ? v : log1pf(__expf(v));   // softplus
      }
      dtp[d4] = o;
    }
  } else {
    float acc[16];
#pragma unroll
    for (int r = 0; r < 16; r++) acc[r] = 0.f;
#pragma unroll 4
    for (int c4 = 0; c4 < 24; c4++){
      float4 xv = xr[c4];
      float xn[4] = {xv.x, xv.y, xv.z, xv.w};
#pragma unroll
      for (int cc = 0; cc < 4; cc++){
        const float4* wc = (const float4*)wT[c4 * 4 + cc];
        float xs = xn[cc];
#pragma unroll
        for (int r4 = 0; r4 < 4; r4++){
          float4 w = wc[r4];
          acc[r4 * 4 + 0] += w.x * xs;
          acc[r4 * 4 + 1] += w.y * xs;
          acc[r4 * 4 + 2] += w.z * xs;
          acc[r4 * 4 + 3] += w.w * xs;
        }
      }
    }
    float* dstb = (part == 1 ? Bsv : Csv) + bkl * NN;
    float4* dp = (float4*)dstb;
#pragma unroll
    for (int r4 = 0; r4 < 4; r4++)
      dp[r4] = make_float4(acc[r4 * 4], acc[r4 * 4 + 1], acc[r4 * 4 + 2], acc[r4 * 4 + 3]);
  }
}

// ---------------- Kernel 4a: chunk-local scan (state + A-product) ----------------
__global__ void k4a_scanA(const float* __restrict__ dt, const float* __restrict__ xc,
                          const float* __restrict__ Bsv, const float* __restrict__ Alog,
                          float* __restrict__ Hc, float* __restrict__ Pc){
  int blk = blockIdx.x;
  int chunk = blk & (NC - 1);
  int k = (blk >> 7) & 3;
  int b = blk >> 9;
  __shared__ float lB[CH * NN];
  {
    const float* src = Bsv + ((size_t)(b * KK + k) * LL + chunk * CH) * NN;
    for (int i = threadIdx.x; i < CH * NN; i += 128) lB[i] = src[i];
  }
  __syncthreads();
  int d = threadIdx.x;
  if (d >= DD) return;
  float a[NN], h[NN], P[NN];
#pragma unroll
  for (int n = 0; n < NN; n++){
    a[n] = -__expf(Alog[(size_t)(k * DD + d) * NN + n]);
    h[n] = 0.f; P[n] = 1.f;
  }
  const float* dtp = dt + ((size_t)(b * KK + k) * LL + chunk * CH) * DD + d;
  for (int s = 0; s < CH; s++){
    int l = chunk * CH + s;
    float dtv = dtp[(size_t)s * DD];
    float xv  = xc[((size_t)b * LL + pos_of(k, l)) * DD + d];
    float du  = dtv * xv;
#pragma unroll
    for (int n = 0; n < NN; n++){
      float e = __expf(dtv * a[n]);
      h[n] = e * h[n] + du * lB[s * NN + n];
      P[n] *= e;
    }
  }
  size_t o = ((((size_t)(b * KK + k) * NC + chunk) * DD) + d) * NN;
#pragma unroll
  for (int n = 0; n < NN; n++){ Hc[o + n] = h[n]; Pc[o + n] = P[n]; }
}

// ---------------- Kernel 4b: serial prefix over chunk summaries ----------------
__global__ void k4b_prefix(const float* __restrict__ Hc, const float* __restrict__ Pc,
                           float* __restrict__ hin){
  int gid = blockIdx.x * 256 + threadIdx.x;
  if (gid >= BB * KK * DD * NN) return;
  int n  = gid & (NN - 1);
  int d  = (gid >> 4) % DD;
  int bk = gid / (NN * DD);
  float hv = 0.f;
  for (int c = 0; c < NC; c++){
    size_t idx = (((size_t)bk * NC + c) * DD + d) * NN + n;
    hin[idx] = hv;
    hv = Pc[idx] * hv + Hc[idx];
  }
}

// ---------------- Kernel 4c: replay chunks with true initial state, emit y ----------------
__global__ void k4c_scanC(const float* __restrict__ dt, const float* __restrict__ xc,
                          const float* __restrict__ Bsv, const float* __restrict__ Csv,
                          const float* __restrict__ Alog, const float* __restrict__ Dsv,
                          const float* __restrict__ hin, float* __restrict__ ys){
  int blk = blockIdx.x;
  int chunk = blk & (NC - 1);
  int k = (blk >> 7) & 3;
  int b = blk >> 9;
  __shared__ float lB[CH * NN];
  __shared__ float lC[CH * NN];
  {
    const float* srcB = Bsv + ((size_t)(b * KK + k) * LL + chunk * CH) * NN;
    const float* srcC = Csv + ((size_t)(b * KK + k) * LL + chunk * CH) * NN;
    for (int i = threadIdx.x; i < CH * NN; i += 128){ lB[i] = srcB[i]; lC[i] = srcC[i]; }
  }
  __syncthreads();
  int d = threadIdx.x;
  if (d >= DD) return;
  float a[NN], h[NN];
  size_t hi = (((size_t)(b * KK + k) * NC + chunk) * DD + d) * NN;
#pragma unroll
  for (int n = 0; n < NN; n++){
    a[n] = -__expf(Alog[(size_t)(k * DD + d) * NN + n]);
    h[n] = hin[hi + n];
  }
  float Dk = Dsv[k * DD + d];
  const float* dtp = dt + ((size_t)(b * KK + k) * LL + chunk * CH) * DD + d;
  float* ysp = ys + ((size_t)(b * KK + k) * LL + chunk * CH) * DD + d;
  for (int s = 0; s < CH; s++){
    int l = chunk * CH + s;
    float dtv = dtp[(size_t)s * DD];
    float xv  = xc[((size_t)b * LL + pos_of(k, l)) * DD + d];
    float du  = dtv * xv;
    float y = 0.f;
#pragma unroll
    for (int n = 0; n < NN; n++){
      float e = __expf(dtv * a[n]);
      h[n] = e * h[n] + du * lB[s * NN + n];
      y += h[n] * lC[s * NN + n];
    }
    ysp[(size_t)s * DD] = y + xv * Dk;
  }
}

// ---------------- Kernel 5a: cross-merge + out-LN + gate -> t ----------------
__global__ void k5a_merge(const float* __restrict__ ys, const float* __restrict__ z,
                          const float* __restrict__ og, const float* __restrict__ ob,
                          float* __restrict__ t){
  int wave = threadIdx.x >> 6, lane = threadIdx.x & 63;
  int pix = blockIdx.x * 4 + wave;
  int b = pix >> 12, pos = pix & (LL - 1);
  int h = pos >> 6, w = pos & 63;
  int lwh = (w << 6) | h;
  const float* base = ys + (size_t)b * KK * LL * DD;

  auto gather = [&](int d) -> float {
    return base[((size_t)(0 * LL) + pos) * DD + d]
         + base[((size_t)(1 * LL) + lwh) * DD + d]
         + base[((size_t)(2 * LL) + (LL - 1 - pos)) * DD + d]
         + base[((size_t)(3 * LL) + (LL - 1 - lwh)) * DD + d];
  };
  float v0 = gather(lane);
  float v1 = (lane < 32) ? gather(64 + lane) : 0.f;
  float s  = wsum(v0 + v1);
  float sq = wsum(v0 * v0 + v1 * v1);
  float mu = s * (1.f / 96.f);
  float var = sq * (1.f / 96.f) - mu * mu;
  float rs = rsqrtf(var + 1e-5f);
  auto fin = [&](float v, int d) -> float {
    float yn = (v - mu) * rs * og[d] + ob[d];
    float zv = z[(size_t)pix * DD + d];
    return yn * siluf(zv);
  };
  t[(size_t)pix * DD + lane] = fin(v0, lane);
  if (lane < 32) t[(size_t)pix * DD + 64 + lane] = fin(v1, 64 + lane);
}

// ---------------- Kernel 5b: out_proj + residual ----------------
__global__ __launch_bounds__(64) void k5b_outproj(const float* __restrict__ t,
                          const float* __restrict__ opw,  // (96,96)
                          const float* __restrict__ x, float* __restrict__ out){
  int tid   = threadIdx.x;
  int tile  = blockIdx.x & 127;
  int chunk = blockIdx.x >> 7;    // 0..3 -> rows [chunk*24, +24)
  __shared__ float wT[96][24];
  const float* Wc = opw + (size_t)chunk * 24 * 96;
  for (int i = tid; i < 24 * 96; i += 64){
    int c = i / 24, r = i - c * 24;
    wT[c][r] = Wc[r * 96 + c];
  }
  __syncthreads();
  int pix = tile * 64 + tid;
  const float4* tr = (const float4*)(t + (size_t)pix * DD);
  float acc[24];
#pragma unroll
  for (int r = 0; r < 24; r++) acc[r] = 0.f;
#pragma unroll 4
  for (int c4 = 0; c4 < 24; c4++){
    float4 tv = tr[c4];
    float xn[4] = {tv.x, tv.y, tv.z, tv.w};
#pragma unroll
    for (int cc = 0; cc < 4; cc++){
      const float4* wc = (const float4*)wT[c4 * 4 + cc];
      float xs = xn[cc];
#pragma unroll
      for (int r4 = 0; r4 < 6; r4++){
        float4 w = wc[r4];
        acc[r4 * 4 + 0] += w.x * xs;
        acc[r4 * 4 + 1] += w.y * xs;
        acc[r4 * 4 + 2] += w.z * xs;
        acc[r4 * 4 + 3] += w.w * xs;
      }
    }
  }
  const float4* xr = (const float4*)(x + (size_t)pix * CC + chunk * 24);
  float4* op = (float4*)(out + (size_t)pix * CC + chunk * 24);
#pragma unroll
  for (int r4 = 0; r4 < 6; r4++){
    float4 xv = xr[r4];
    op[r4] = make_float4(xv.x + acc[r4 * 4], xv.y + acc[r4 * 4 + 1],
                         xv.z + acc[r4 * 4 + 2], xv.w + acc[r4 * 4 + 3]);
  }
}

extern "C" void kernel_launch(void* const* d_in, const int* in_sizes, int n_in,
                              void* d_out, int out_size, void* d_ws, size_t ws_size,
                              hipStream_t stream){
  const float* x    = (const float*)d_in[0];
  const float* ng   = (const float*)d_in[1];
  const float* nb   = (const float*)d_in[2];
  const float* ipw  = (const float*)d_in[3];
  const float* cw   = (const float*)d_in[4];
  const float* cb   = (const float*)d_in[5];
  const float* xpw  = (const float*)d_in[6];
  const float* dtw  = (const float*)d_in[7];
  const float* dtb  = (const float*)d_in[8];
  const float* Alog = (const float*)d_in[9];
  const float* Dsv  = (const float*)d_in[10];
  const float* og   = (const float*)d_in[11];
  const float* ob   = (const float*)d_in[12];
  const float* opw  = (const float*)d_in[13];
  float* out = (float*)d_out;

  float* ws = (float*)d_ws;
  float* xh  = ws;
  float* zz  = xh  + (size_t)BB * LL * DD;
  float* xc  = zz  + (size_t)BB * LL * DD;
  float* dt  = xc  + (size_t)BB * LL * DD;
  float* Bs  = dt  + (size_t)BB * KK * LL * DD;
  float* Cs  = Bs  + (size_t)BB * KK * LL * NN;
  float* Hc  = Cs  + (size_t)BB * KK * LL * NN;
  float* Pc  = Hc  + (size_t)BB * KK * NC * DD * NN;
  float* hin = Pc  + (size_t)BB * KK * NC * DD * NN;
  float* ys  = hin + (size_t)BB * KK * NC * DD * NN;
  float* t   = xh;   // xh dead after k2

  k1_ln_inproj<<<dim3(256), dim3(256), 0, stream>>>(x, ng, nb, ipw, xh, zz);
  k2_conv     <<<dim3(BB * LL * DD / 256), dim3(256), 0, stream>>>(xh, cw, cb, xc);
  k3_xproj    <<<dim3(12 * 64), dim3(128), 0, stream>>>(xc, xpw, dtw, dtb, dt, Bs, Cs);
  k4a_scanA   <<<dim3(BB * KK * NC), dim3(128), 0, stream>>>(dt, xc, Bs, Alog, Hc, Pc);
  k4b_prefix  <<<dim3((BB * KK * DD * NN + 255) / 256), dim3(256), 0, stream>>>(Hc, Pc, hin);
  k4c_scanC   <<<dim3(BB * KK * NC), dim3(128), 0, stream>>>(dt, xc, Bs, Cs, Alog, Dsv, hin, ys);
  k5a_merge   <<<dim3(BB * LL / 4), dim3(256), 0, stream>>>(ys, zz, og, ob, t);
  k5b_outproj <<<dim3(512), dim3(64), 0, stream>>>(t, opw, x, out);
}